// Round 2
// baseline (13212.895 us; speedup 1.0000x reference)
//
#include <hip/hip_runtime.h>
#include <stdint.h>

#define TSTEPS 512

typedef __attribute__((ext_vector_type(8))) _Float16 half8;
typedef __attribute__((ext_vector_type(4))) _Float16 half4;
typedef __attribute__((ext_vector_type(4))) float f32x4;
typedef __attribute__((ext_vector_type(4))) float float4v;

static __device__ __forceinline__ float sigm(float x) { return 1.f / (1.f + __expf(-x)); }
static __device__ __forceinline__ float tanh_(float x) {
  x = fminf(15.f, fmaxf(-15.f, x));
  float e = __expf(-2.f * x);
  return (1.f - e) / (1.f + e);
}
static __device__ __forceinline__ half8 ld8(const _Float16* p) { return *(const half8*)p; }
static __device__ __forceinline__ f32x4 MFMA(half8 a, half8 b, f32x4 c) {
  return __builtin_amdgcn_mfma_f32_16x16x32_f16(a, b, c, 0, 0, 0);
}

// ---------------- f32 -> f16 conversion / init ----------------
__global__ __launch_bounds__(256) void kconv(
    const float* __restrict__ xs, const float* __restrict__ wih,
    const float* __restrict__ wxh, const float* __restrict__ whhf,
    const float* __restrict__ wrf, const float* __restrict__ h0,
    _Float16* __restrict__ xs_h, _Float16* __restrict__ wcat,
    _Float16* __restrict__ whh, _Float16* __restrict__ wr,
    _Float16* __restrict__ h_h) {
  const long n1 = 8388608;   // xs / 4
  const long n2 = 1048576;   // wcat / 4
  const long n3 = 786432;    // whh / 4
  const long n4 = 262144;    // wr / 4
  const long n5 = 16384;     // h0 / 4
  const long total = n1 + n2 + n3 + n4 + n5;
  for (long i = (long)blockIdx.x * 256 + threadIdx.x; i < total; i += (long)gridDim.x * 256) {
    const float* s; _Float16* d;
    if (i < n1) { s = xs + i * 4; d = xs_h + i * 4; }
    else if (i < n1 + n2) {
      long e = (i - n1) * 4;
      s = (e < 3145728) ? (wih + e) : (wxh + (e - 3145728));
      d = wcat + e;
    } else if (i < n1 + n2 + n3) { long e = (i - n1 - n2) * 4; s = whhf + e; d = whh + e; }
    else if (i < n1 + n2 + n3 + n4) { long e = (i - n1 - n2 - n3) * 4; s = wrf + e; d = wr + e; }
    else { long e = (i - n1 - n2 - n3 - n4) * 4; s = h0 + e; d = h_h + e; }
    float4v v = *(const float4v*)s;
    half4 o = { (_Float16)v.x, (_Float16)v.y, (_Float16)v.z, (_Float16)v.w };
    *(half4*)d = o;
  }
}

// ---------------- big input-side GEMM: xgh[32768][4096] = xs @ [W_ih;W_xh]^T + bias ----------------
__global__ __launch_bounds__(256) void kgemm(
    const _Float16* __restrict__ X, const _Float16* __restrict__ W,
    const float* __restrict__ b_ih, const float* __restrict__ b_xh,
    _Float16* __restrict__ C) {
  __shared__ _Float16 As[128 * 40], Bs[128 * 40];
  const int tid = threadIdx.x;
  const int lane = tid & 63;
  const int w = tid >> 6;
  const int wm = (w >> 1) * 64, wn = (w & 1) * 64;
  const int bn = blockIdx.x * 128;
  const int bm = blockIdx.y * 128;
  const int arow = tid >> 2;
  const int kk8 = (tid & 3) * 8;
  const int fr = lane & 15, fq = lane >> 4;
  const f32x4 zero = {0.f, 0.f, 0.f, 0.f};
  f32x4 acc[4][4];
  #pragma unroll
  for (int a = 0; a < 4; a++)
    #pragma unroll
    for (int b = 0; b < 4; b++) acc[a][b] = zero;
  for (int kt = 0; kt < 1024; kt += 32) {
    __syncthreads();
    #pragma unroll
    for (int j = 0; j < 2; j++) {
      int r = j * 64 + arow;
      *(half8*)(As + r * 40 + kk8) = ld8(X + (size_t)(bm + r) * 1024 + kt + kk8);
      *(half8*)(Bs + r * 40 + kk8) = ld8(W + (size_t)(bn + r) * 1024 + kt + kk8);
    }
    __syncthreads();
    half8 af[4], bfr[4];
    #pragma unroll
    for (int i = 0; i < 4; i++) {
      af[i]  = *(const half8*)(As + (wm + i * 16 + fr) * 40 + fq * 8);
      bfr[i] = *(const half8*)(Bs + (wn + i * 16 + fr) * 40 + fq * 8);
    }
    #pragma unroll
    for (int mi = 0; mi < 4; mi++)
      #pragma unroll
      for (int ni = 0; ni < 4; ni++)
        acc[mi][ni] = MFMA(af[mi], bfr[ni], acc[mi][ni]);
  }
  #pragma unroll
  for (int mi = 0; mi < 4; mi++)
    #pragma unroll
    for (int ni = 0; ni < 4; ni++) {
      int col = bn + wn + ni * 16 + fr;
      float bias = (col < 3072) ? b_ih[col] : b_xh[col - 3072];
      #pragma unroll
      for (int r = 0; r < 4; r++) {
        int row = bm + wm + mi * 16 + fq * 4 + r;
        C[(size_t)row * 4096 + col] = (_Float16)(acc[mi][ni][r] + bias);
      }
    }
}

// ---------------- split-phase grid barrier (monotonic counter, agent scope) ----------------
// arrive: drain stores, wg-sync, one RELEASE add (single L2 writeback).
// wait:   RELAXED spin (no per-poll invalidate!), then ONE ACQUIRE load (single L2 inv).
__device__ __forceinline__ void gbar_arrive(unsigned* bar) {
  asm volatile("s_waitcnt vmcnt(0)" ::: "memory");
  __syncthreads();
  if (threadIdx.x == 0)
    __hip_atomic_fetch_add(bar, 1u, __ATOMIC_RELEASE, __HIP_MEMORY_SCOPE_AGENT);
}
__device__ __forceinline__ void gbar_wait(unsigned* bar, unsigned target) {
  if (threadIdx.x == 0) {
    while (__hip_atomic_load(bar, __ATOMIC_RELAXED, __HIP_MEMORY_SCOPE_AGENT) < target)
      __builtin_amdgcn_s_sleep(2);
    (void)__hip_atomic_load(bar, __ATOMIC_ACQUIRE, __HIP_MEMORY_SCOPE_AGENT);
  }
  __syncthreads();
}

// ---------------- persistent recurrent kernel ----------------
// 64 wgs x 256 thr. wg g owns h-cols [16g,16g+16). Wave ki holds K-slice [256ki,256ki+256)
// of W_hh rows (r,z,e for its cols) + W_r rows in VGPRs. Split-K partials reduced in LDS.
__global__ __launch_bounds__(256, 1) void krec(
    const _Float16* __restrict__ xgh, const float* __restrict__ ms,
    const _Float16* __restrict__ whh, const _Float16* __restrict__ wr,
    const float* __restrict__ b_hh, const float* __restrict__ b_r,
    const float* __restrict__ h0,
    _Float16* __restrict__ h_h, _Float16* __restrict__ rh_h,
    float* __restrict__ out, unsigned* __restrict__ bar) {
  const int g = blockIdx.x;
  const int tid = threadIdx.x;
  const int lane = tid & 63;
  const int ki = tid >> 6;
  const int fr = lane & 15, fq = lane >> 4;
  const int cbase = g * 16;

  __shared__ float red[4 * 64 * 49];  // pitch 49 (phase A) / 17 (phase B)

  // weight fragments -> registers (held across all 512 steps)
  half8 wfA[3][8], wfB[8];
  {
    const _Float16* ba = whh + (size_t)(cbase + fr) * 1024 + ki * 256 + fq * 8;
    #pragma unroll
    for (int nt = 0; nt < 3; nt++)
      #pragma unroll
      for (int ks = 0; ks < 8; ks++)
        wfA[nt][ks] = ld8(ba + (size_t)nt * 1048576 + ks * 32);
    const _Float16* bb = wr + (size_t)(cbase + fr) * 1024 + ki * 256 + fq * 8;
    #pragma unroll
    for (int ks = 0; ks < 8; ks++) wfB[ks] = ld8(bb + ks * 32);
  }

  // per-thread ownership for elementwise math: c = tid&15, m = (tid>>4) + 16*i
  const int c = tid & 15;
  const int mb = tid >> 4;
  const int gc = cbase + c;
  const float bhr = b_hh[gc], bhz = b_hh[1024 + gc], bhe = b_hh[2048 + gc];
  const float brr = b_r[gc];
  float hreg[4];
  #pragma unroll
  for (int i = 0; i < 4; i++) hreg[i] = h0[(size_t)(mb + 16 * i) * 1024 + gc];

  const f32x4 zero = {0.f, 0.f, 0.f, 0.f};

  // prefetched per-step inputs (loaded in barrier overlap windows)
  float pxr[4], pxz[4], pxe[4], pxh[4], ptm[4];
  {
    const _Float16* xg_t = xgh;
    #pragma unroll
    for (int i = 0; i < 4; i++) {
      const int m = mb + 16 * i;
      pxr[i] = (float)xg_t[(size_t)m * 4096 + gc];
      pxz[i] = (float)xg_t[(size_t)m * 4096 + 1024 + gc];
      pxe[i] = (float)xg_t[(size_t)m * 4096 + 2048 + gc];
      pxh[i] = (float)xg_t[(size_t)m * 4096 + 3072 + gc];
      ptm[i] = tanh_(ms[(size_t)m * 1024 + gc]);
    }
  }

  #pragma clang loop unroll(disable)
  for (int t = 0; t < TSTEPS; t++) {
    // ---- phase A: gates = sigmoid(xg + h @ Whh^T + b_hh); publish rh = r*h
    f32x4 accA[4][3];
    #pragma unroll
    for (int mt = 0; mt < 4; mt++)
      #pragma unroll
      for (int nt = 0; nt < 3; nt++) accA[mt][nt] = zero;
    {
      const _Float16* hb = h_h + fr * 1024 + ki * 256 + fq * 8;
      #pragma unroll
      for (int ks = 0; ks < 8; ks++) {
        half8 a[4];
        #pragma unroll
        for (int mt = 0; mt < 4; mt++) a[mt] = ld8(hb + mt * 16384 + ks * 32);
        #pragma unroll
        for (int mt = 0; mt < 4; mt++)
          #pragma unroll
          for (int nt = 0; nt < 3; nt++)
            accA[mt][nt] = MFMA(a[mt], wfA[nt][ks], accA[mt][nt]);
      }
    }
    __syncthreads();  // protect red[] reuse from previous iteration's readers
    #pragma unroll
    for (int mt = 0; mt < 4; mt++)
      #pragma unroll
      for (int nt = 0; nt < 3; nt++)
        #pragma unroll
        for (int r = 0; r < 4; r++)
          red[(ki * 64 + mt * 16 + fq * 4 + r) * 49 + nt * 16 + fr] = accA[mt][nt][r];
    __syncthreads();
    float zz[4], ee[4];
    #pragma unroll
    for (int i = 0; i < 4; i++) {
      const int m = mb + 16 * i;
      float sr = 0.f, sz = 0.f, se = 0.f;
      #pragma unroll
      for (int w = 0; w < 4; w++) {
        const float* p = red + (w * 64 + m) * 49;
        sr += p[c]; sz += p[16 + c]; se += p[32 + c];
      }
      float rg = sigm(pxr[i] + sr + bhr);
      zz[i] = sigm(pxz[i] + sz + bhz);
      ee[i] = sigm(pxe[i] + se + bhe);
      rh_h[m * 1024 + gc] = (_Float16)(rg * hreg[i]);
    }
    gbar_arrive(bar);
    gbar_wait(bar, (unsigned)(2 * t + 1) * 64u);

    // ---- phase B: ht_hat = tanh(xh + rh @ Wr^T + b_r); h = z*h + (1-z)*ht_hat + e*tanh(ms)
    f32x4 accB[4];
    #pragma unroll
    for (int mt = 0; mt < 4; mt++) accB[mt] = zero;
    {
      const _Float16* rb = rh_h + fr * 1024 + ki * 256 + fq * 8;
      #pragma unroll
      for (int ks = 0; ks < 8; ks++)
        #pragma unroll
        for (int mt = 0; mt < 4; mt++)
          accB[mt] = MFMA(ld8(rb + mt * 16384 + ks * 32), wfB[ks], accB[mt]);
    }
    __syncthreads();  // red[] reuse guard
    #pragma unroll
    for (int mt = 0; mt < 4; mt++)
      #pragma unroll
      for (int r = 0; r < 4; r++)
        red[(ki * 64 + mt * 16 + fq * 4 + r) * 17 + fr] = accB[mt][r];
    __syncthreads();
    float* outT = out + (size_t)t * 65536;
    float hnew[4];
    #pragma unroll
    for (int i = 0; i < 4; i++) {
      const int m = mb + 16 * i;
      float s = 0.f;
      #pragma unroll
      for (int w = 0; w < 4; w++) s += red[(w * 64 + m) * 17 + c];
      float hh = tanh_(pxh[i] + s + brr);
      float hn = zz[i] * hreg[i] + (1.f - zz[i]) * hh + ee[i] * ptm[i];
      hreg[i] = hn;
      hnew[i] = hn;
      h_h[m * 1024 + gc] = (_Float16)hn;
    }
    #pragma unroll
    for (int i = 0; i < 4; i++)
      __builtin_nontemporal_store(hnew[i], outT + (mb + 16 * i) * 1024 + gc);
    gbar_arrive(bar);
    // overlap window: prefetch next step's xg/ms while laggard wgs arrive
    if (t + 1 < TSTEPS) {
      const _Float16* xg_n = xgh + (size_t)(t + 1) * 262144;
      #pragma unroll
      for (int i = 0; i < 4; i++) {
        const int m = mb + 16 * i;
        pxr[i] = (float)xg_n[(size_t)m * 4096 + gc];
        pxz[i] = (float)xg_n[(size_t)m * 4096 + 1024 + gc];
        pxe[i] = (float)xg_n[(size_t)m * 4096 + 2048 + gc];
        pxh[i] = (float)xg_n[(size_t)m * 4096 + 3072 + gc];
        ptm[i] = tanh_(ms[(size_t)(t + 1) * 65536 + m * 1024 + gc]);
      }
    }
    gbar_wait(bar, (unsigned)(2 * t + 2) * 64u);
  }
  // h_last
  float* outL = out + (size_t)TSTEPS * 65536;
  #pragma unroll
  for (int i = 0; i < 4; i++) outL[(mb + 16 * i) * 1024 + gc] = hreg[i];
}

extern "C" void kernel_launch(void* const* d_in, const int* in_sizes, int n_in,
                              void* d_out, int out_size, void* d_ws, size_t ws_size,
                              hipStream_t stream) {
  const float* xs   = (const float*)d_in[0];
  const float* ms   = (const float*)d_in[1];
  const float* h0   = (const float*)d_in[2];
  const float* W_ih = (const float*)d_in[3];
  const float* b_ih = (const float*)d_in[4];
  const float* W_hh = (const float*)d_in[5];
  const float* b_hh = (const float*)d_in[6];
  const float* W_xh = (const float*)d_in[7];
  const float* b_xh = (const float*)d_in[8];
  const float* W_r  = (const float*)d_in[9];
  const float* b_r  = (const float*)d_in[10];

  char* ws = (char*)d_ws;
  size_t off = 0;
  _Float16* xs_h = (_Float16*)(ws + off); off += 67108864;   // [32768][1024] f16
  _Float16* wcat = (_Float16*)(ws + off); off += 8388608;    // [4096][1024] f16
  _Float16* whh  = (_Float16*)(ws + off); off += 6291456;    // [3072][1024] f16
  _Float16* wr   = (_Float16*)(ws + off); off += 2097152;    // [1024][1024] f16
  _Float16* xgh  = (_Float16*)(ws + off); off += 268435456;  // [32768][4096] f16
  _Float16* h_h  = (_Float16*)(ws + off); off += 131072;     // [64][1024] f16
  _Float16* rh_h = (_Float16*)(ws + off); off += 131072;     // [64][1024] f16
  unsigned* bar  = (unsigned*)(ws + off); off += 256;        // barrier counter

  hipMemsetAsync(bar, 0, 256, stream);
  kconv<<<2048, 256, 0, stream>>>(xs, W_ih, W_xh, W_hh, W_r, h0, xs_h, wcat, whh, wr, h_h);
  kgemm<<<dim3(32, 256), 256, 0, stream>>>(xs_h, wcat, b_ih, b_xh, xgh);
  krec<<<64, 256, 0, stream>>>(xgh, ms, whh, wr, b_hh, b_r, h0, h_h, rh_h, (float*)d_out, bar);
}

// Round 4
// 4432.249 us; speedup vs baseline: 2.9811x; 2.9811x over previous
//
#include <hip/hip_runtime.h>
#include <stdint.h>

#define TSTEPS 512

typedef __attribute__((ext_vector_type(8))) _Float16 half8;
typedef __attribute__((ext_vector_type(4))) _Float16 half4;
typedef __attribute__((ext_vector_type(4))) float f32x4;
typedef __attribute__((ext_vector_type(4))) float float4v;
typedef unsigned long long u64;

static __device__ __forceinline__ float sigm(float x) { return 1.f / (1.f + __expf(-x)); }
static __device__ __forceinline__ float tanh_(float x) {
  x = fminf(15.f, fmaxf(-15.f, x));
  float e = __expf(-2.f * x);
  return (1.f - e) / (1.f + e);
}
static __device__ __forceinline__ half8 ld8(const _Float16* p) { return *(const half8*)p; }
static __device__ __forceinline__ f32x4 MFMA(half8 a, half8 b, f32x4 c) {
  return __builtin_amdgcn_mfma_f32_16x16x32_f16(a, b, c, 0, 0, 0);
}

// ---- cross-XCD message passing: agent-scope RELAXED atomics only (no fences).
// These execute/read at the MALL (verified working in r1/r2's barrier spins);
// no wbl2/inv tag sweeps. Ordering: vmcnt(0) before the barrier arrive-add.
struct U64x2 { u64 x, y; };
static __device__ __forceinline__ half8 ld_msg16(const u64* p) {
  u64 a = __hip_atomic_load(p,     __ATOMIC_RELAXED, __HIP_MEMORY_SCOPE_AGENT);
  u64 b = __hip_atomic_load(p + 1, __ATOMIC_RELAXED, __HIP_MEMORY_SCOPE_AGENT);
  U64x2 u{a, b};
  return __builtin_bit_cast(half8, u);
}
static __device__ __forceinline__ void st_msg8(u64* p, u64 v) {
  __hip_atomic_store(p, v, __ATOMIC_RELAXED, __HIP_MEMORY_SCOPE_AGENT);
}

// ---------------- f32 -> f16 conversion / init ----------------
__global__ __launch_bounds__(256) void kconv(
    const float* __restrict__ xs, const float* __restrict__ wih,
    const float* __restrict__ wxh, const float* __restrict__ whhf,
    const float* __restrict__ wrf, const float* __restrict__ h0,
    _Float16* __restrict__ xs_h, _Float16* __restrict__ wcat,
    _Float16* __restrict__ whh, _Float16* __restrict__ wr,
    _Float16* __restrict__ hx) {
  const long n1 = 8388608;   // xs / 4
  const long n2 = 1048576;   // wcat / 4
  const long n3 = 786432;    // whh / 4
  const long n4 = 262144;    // wr / 4
  const long n5 = 16384;     // h0 / 4 -> hx f16 [64][1024]
  const long total = n1 + n2 + n3 + n4 + n5;
  for (long i = (long)blockIdx.x * 256 + threadIdx.x; i < total; i += (long)gridDim.x * 256) {
    const float* s; _Float16* d;
    if (i < n1) { s = xs + i * 4; d = xs_h + i * 4; }
    else if (i < n1 + n2) {
      long e = (i - n1) * 4;
      s = (e < 3145728) ? (wih + e) : (wxh + (e - 3145728));
      d = wcat + e;
    } else if (i < n1 + n2 + n3) { long e = (i - n1 - n2) * 4; s = whhf + e; d = whh + e; }
    else if (i < n1 + n2 + n3 + n4) { long e = (i - n1 - n2 - n3) * 4; s = wrf + e; d = wr + e; }
    else { long e = (i - n1 - n2 - n3 - n4) * 4; s = h0 + e; d = hx + e; }
    float4v v = *(const float4v*)s;
    half4 o = { (_Float16)v.x, (_Float16)v.y, (_Float16)v.z, (_Float16)v.w };
    *(half4*)d = o;
  }
}

// ---------------- big input-side GEMM: xgh[32768][4096] = xs @ [W_ih;W_xh]^T + bias ----------------
__global__ __launch_bounds__(256) void kgemm(
    const _Float16* __restrict__ X, const _Float16* __restrict__ W,
    const float* __restrict__ b_ih, const float* __restrict__ b_xh,
    _Float16* __restrict__ C) {
  __shared__ _Float16 As[128 * 40], Bs[128 * 40];
  const int tid = threadIdx.x;
  const int lane = tid & 63;
  const int w = tid >> 6;
  const int wm = (w >> 1) * 64, wn = (w & 1) * 64;
  const int bn = blockIdx.x * 128;
  const int bm = blockIdx.y * 128;
  const int arow = tid >> 2;
  const int kk8 = (tid & 3) * 8;
  const int fr = lane & 15, fq = lane >> 4;
  const f32x4 zero = {0.f, 0.f, 0.f, 0.f};
  f32x4 acc[4][4];
  #pragma unroll
  for (int a = 0; a < 4; a++)
    #pragma unroll
    for (int b = 0; b < 4; b++) acc[a][b] = zero;
  for (int kt = 0; kt < 1024; kt += 32) {
    __syncthreads();
    #pragma unroll
    for (int j = 0; j < 2; j++) {
      int r = j * 64 + arow;
      *(half8*)(As + r * 40 + kk8) = ld8(X + (size_t)(bm + r) * 1024 + kt + kk8);
      *(half8*)(Bs + r * 40 + kk8) = ld8(W + (size_t)(bn + r) * 1024 + kt + kk8);
    }
    __syncthreads();
    half8 af[4], bfr[4];
    #pragma unroll
    for (int i = 0; i < 4; i++) {
      af[i]  = *(const half8*)(As + (wm + i * 16 + fr) * 40 + fq * 8);
      bfr[i] = *(const half8*)(Bs + (wn + i * 16 + fr) * 40 + fq * 8);
    }
    #pragma unroll
    for (int mi = 0; mi < 4; mi++)
      #pragma unroll
      for (int ni = 0; ni < 4; ni++)
        acc[mi][ni] = MFMA(af[mi], bfr[ni], acc[mi][ni]);
  }
  #pragma unroll
  for (int mi = 0; mi < 4; mi++)
    #pragma unroll
    for (int ni = 0; ni < 4; ni++) {
      int col = bn + wn + ni * 16 + fr;
      float bias = (col < 3072) ? b_ih[col] : b_xh[col - 3072];
      #pragma unroll
      for (int r = 0; r < 4; r++) {
        int row = bm + wm + mi * 16 + fq * 4 + r;
        C[(size_t)row * 4096 + col] = (_Float16)(acc[mi][ni][r] + bias);
      }
    }
}

// ---------------- barrier: relaxed agent atomics only (no wbl2/inv sweeps) ----------------
static __device__ __forceinline__ void bar_arrive(unsigned* bp) {
  asm volatile("s_waitcnt vmcnt(0)" ::: "memory");  // all msg stores acked at MALL
  __syncthreads();
  if (threadIdx.x == 0)
    __hip_atomic_fetch_add(bp, 1u, __ATOMIC_RELAXED, __HIP_MEMORY_SCOPE_AGENT);
}
static __device__ __forceinline__ void bar_wait(unsigned* bp, unsigned tgt) {
  if (threadIdx.x == 0)
    while (__hip_atomic_load(bp, __ATOMIC_RELAXED, __HIP_MEMORY_SCOPE_AGENT) < tgt)
      __builtin_amdgcn_s_sleep(1);
  __syncthreads();
  asm volatile("" ::: "memory");
}

// ---------------- persistent recurrent kernel ----------------
// 4 groups x 32 wgs x 512 thr (128 wgs, all resident on 256 CUs).
// Group owns 16 batch rows; wg owns 32 h-cols (full K=1024 of its W_hh/W_r
// rows in VGPRs). Wave w = K-slice [128w,128w+128); split-K reduced in LDS.
// Cross-wg h/rh exchange: u64 relaxed agent atomics through the MALL.
#define TP 272  // LDS reduce: tile stride (f32)
#define RP 17   // LDS reduce: row pitch (f32)

__global__ __launch_bounds__(512) void krec(
    const _Float16* __restrict__ xgh, const float* __restrict__ ms,
    const _Float16* __restrict__ whh, const _Float16* __restrict__ wr,
    const float* __restrict__ b_hh, const float* __restrict__ b_r,
    const float* __restrict__ h0,
    _Float16* __restrict__ hx, _Float16* __restrict__ rhx,
    float* __restrict__ out, unsigned* __restrict__ ctr) {
  __shared__ float red[48 * TP];      // 8 waves x 6 tiles, padded
  __shared__ _Float16 hsh[512];
  const int tid = threadIdx.x;
  const int lane = tid & 63, w = tid >> 6;
  const int fr = lane & 15, fq = lane >> 4;
  const int g = (int)blockIdx.x >> 5;
  const int colbase = ((int)blockIdx.x & 31) * 32;
  unsigned* bar = ctr + g * 64;

  // ---- weight fragments -> VGPRs (held across all 512 steps)
  half8 wA[6][4], wB[2][4];
  #pragma unroll
  for (int nt = 0; nt < 6; nt++)
    #pragma unroll
    for (int ks = 0; ks < 4; ks++)
      wA[nt][ks] = ld8(whh + (size_t)((nt >> 1) * 1024 + colbase + (nt & 1) * 16 + fr) * 1024
                            + w * 128 + ks * 32 + fq * 8);
  #pragma unroll
  for (int nt = 0; nt < 2; nt++)
    #pragma unroll
    for (int ks = 0; ks < 4; ks++)
      wB[nt][ks] = ld8(wr + (size_t)(colbase + nt * 16 + fr) * 1024
                           + w * 128 + ks * 32 + fq * 8);

  // ---- every thread owns one (row b, col cc) cell
  const int b = tid >> 5, cc = tid & 31;
  const int gc = colbase + cc;
  const int gm = g * 16 + b;
  const float bhr = b_hh[gc], bhz = b_hh[1024 + gc], bhe = b_hh[2048 + gc];
  const float brr = b_r[gc];
  float hreg = h0[(size_t)gm * 1024 + gc];

  // msg-exchange addresses
  const u64* hx64  = (const u64*)hx  + (((g * 16 + fr) * 1024 + w * 128 + fq * 8) >> 2);
  const u64* rhx64 = (const u64*)rhx + (((g * 16 + fr) * 1024 + w * 128 + fq * 8) >> 2);
  u64* hpub  = (u64*)hx  + (((g * 16 + (tid >> 3)) * 1024 + colbase + (tid & 7) * 4) >> 2);
  u64* rhpub = (u64*)rhx + (((g * 16 + (tid >> 3)) * 1024 + colbase + (tid & 7) * 4) >> 2);
  const _Float16* hsrc = hsh + (tid >> 3) * 32 + (tid & 7) * 4;

  const f32x4 zero = {0.f, 0.f, 0.f, 0.f};

  // prefetched per-step inputs
  float pxr, pxz, pxe, pxh, ptm;
  {
    const _Float16* xp = xgh + (size_t)gm * 4096;
    pxr = (float)xp[gc]; pxz = (float)xp[1024 + gc];
    pxe = (float)xp[2048 + gc]; pxh = (float)xp[3072 + gc];
    ptm = tanh_(ms[(size_t)gm * 1024 + gc]);
  }

  #pragma clang loop unroll(disable)
  for (int t = 0; t < TSTEPS; t++) {
    // ======== phase A: gates = sigmoid(xg + h @ Whh^T + b_hh); publish rh = r*h
    half8 av[4];
    if (t == 0) {
      #pragma unroll
      for (int ks = 0; ks < 4; ks++)
        av[ks] = ld8(hx + (g * 16 + fr) * 1024 + w * 128 + ks * 32 + fq * 8);
    } else {
      #pragma unroll
      for (int ks = 0; ks < 4; ks++)
        av[ks] = ld_msg16(hx64 + ks * 8);
    }
    f32x4 accA[6];
    #pragma unroll
    for (int nt = 0; nt < 6; nt++) accA[nt] = zero;
    #pragma unroll
    for (int ks = 0; ks < 4; ks++)
      #pragma unroll
      for (int nt = 0; nt < 6; nt++)
        accA[nt] = MFMA(av[ks], wA[nt][ks], accA[nt]);
    #pragma unroll
    for (int nt = 0; nt < 6; nt++)
      #pragma unroll
      for (int r = 0; r < 4; r++)
        red[(w * 6 + nt) * TP + (fq * 4 + r) * RP + fr] = accA[nt][r];
    __syncthreads();
    float sr = pxr + bhr, sz = pxz + bhz, se = pxe + bhe;
    {
      const int boff = b * RP + (cc & 15) + (cc >> 4) * TP;
      #pragma unroll
      for (int w8 = 0; w8 < 8; w8++) {
        const float* rp = red + w8 * 6 * TP + boff;
        sr += rp[0]; sz += rp[2 * TP]; se += rp[4 * TP];
      }
    }
    float rg = sigm(sr);
    float zz = sigm(sz), ee = sigm(se);
    hsh[tid] = (_Float16)(rg * hreg);
    __syncthreads();
    if (tid < 128)
      st_msg8(rhpub, __builtin_bit_cast(u64, *(const half4*)hsrc));
    bar_arrive(bar);
    // overlap: prefetch next step's xg/ms while laggards arrive
    float nxr = 0.f, nxz = 0.f, nxe = 0.f, nxh = 0.f, ntm = 0.f;
    if (t + 1 < TSTEPS) {
      const _Float16* xp = xgh + (size_t)((t + 1) * 64 + gm) * 4096;
      nxr = (float)xp[gc]; nxz = (float)xp[1024 + gc];
      nxe = (float)xp[2048 + gc]; nxh = (float)xp[3072 + gc];
      ntm = tanh_(ms[(size_t)(t + 1) * 65536 + gm * 1024 + gc]);
    }
    bar_wait(bar, (unsigned)(64 * t + 32));

    // ======== phase B: hhat = tanh(xh + rh @ Wr^T + b_r); h update + publish
    half8 bv[4];
    #pragma unroll
    for (int ks = 0; ks < 4; ks++)
      bv[ks] = ld_msg16(rhx64 + ks * 8);
    f32x4 accB[2];
    #pragma unroll
    for (int nt = 0; nt < 2; nt++) accB[nt] = zero;
    #pragma unroll
    for (int ks = 0; ks < 4; ks++)
      #pragma unroll
      for (int nt = 0; nt < 2; nt++)
        accB[nt] = MFMA(bv[ks], wB[nt][ks], accB[nt]);
    __syncthreads();  // red[] reuse guard (phase A readers done)
    #pragma unroll
    for (int nt = 0; nt < 2; nt++)
      #pragma unroll
      for (int r = 0; r < 4; r++)
        red[(w * 6 + nt) * TP + (fq * 4 + r) * RP + fr] = accB[nt][r];
    __syncthreads();
    float s = pxh + brr;
    {
      const int boff = b * RP + (cc & 15) + (cc >> 4) * TP;
      #pragma unroll
      for (int w8 = 0; w8 < 8; w8++) s += red[w8 * 6 * TP + boff];
    }
    float hh = tanh_(s);
    float hn = zz * hreg + (1.f - zz) * hh + ee * ptm;
    hreg = hn;
    out[(size_t)t * 65536 + gm * 1024 + gc] = hn;
    hsh[tid] = (_Float16)hn;
    __syncthreads();
    if (tid < 128)
      st_msg8(hpub, __builtin_bit_cast(u64, *(const half4*)hsrc));
    bar_arrive(bar);
    bar_wait(bar, (unsigned)(64 * t + 64));
    pxr = nxr; pxz = nxz; pxe = nxe; pxh = nxh; ptm = ntm;
  }
  out[(size_t)TSTEPS * 65536 + gm * 1024 + gc] = hreg;
}

extern "C" void kernel_launch(void* const* d_in, const int* in_sizes, int n_in,
                              void* d_out, int out_size, void* d_ws, size_t ws_size,
                              hipStream_t stream) {
  const float* xs   = (const float*)d_in[0];
  const float* ms   = (const float*)d_in[1];
  const float* h0   = (const float*)d_in[2];
  const float* W_ih = (const float*)d_in[3];
  const float* b_ih = (const float*)d_in[4];
  const float* W_hh = (const float*)d_in[5];
  const float* b_hh = (const float*)d_in[6];
  const float* W_xh = (const float*)d_in[7];
  const float* b_xh = (const float*)d_in[8];
  const float* W_r  = (const float*)d_in[9];
  const float* b_r  = (const float*)d_in[10];

  char* ws = (char*)d_ws;
  size_t off = 0;
  _Float16* xs_h = (_Float16*)(ws + off); off += 67108864;   // [32768][1024] f16
  _Float16* wcat = (_Float16*)(ws + off); off += 8388608;    // [4096][1024] f16
  _Float16* whh  = (_Float16*)(ws + off); off += 6291456;    // [3072][1024] f16
  _Float16* wr   = (_Float16*)(ws + off); off += 2097152;    // [1024][1024] f16
  _Float16* xgh  = (_Float16*)(ws + off); off += 268435456;  // [32768][4096] f16
  _Float16* hx   = (_Float16*)(ws + off); off += 131072;     // [64][1024] f16
  _Float16* rhx  = (_Float16*)(ws + off); off += 131072;     // [64][1024] f16
  unsigned* ctr  = (unsigned*)(ws + off); off += 1024;       // 4 group barriers

  hipMemsetAsync(ctr, 0, 1024, stream);
  kconv<<<2048, 256, 0, stream>>>(xs, W_ih, W_xh, W_hh, W_r, h0,
                                  xs_h, wcat, whh, wr, hx);
  kgemm<<<dim3(32, 256), 256, 0, stream>>>(xs_h, wcat, b_ih, b_xh, xgh);
  krec<<<128, 512, 0, stream>>>(xgh, ms, whh, wr, b_hh, b_r, h0,
                                hx, rhx, (float*)d_out, ctr);
}